// Round 3
// baseline (623.641 us; speedup 1.0000x reference)
//
#include <hip/hip_runtime.h>

// x: (64,3,512,512) fp32 -> conv3x3 VALID + avgpool2x2 + sigmoid + per-batch sum.
// Fused stride-2 4x4 conv: w_eff[ky][kx] = 0.25*sum_{py,px in {0,1}} w[ky-py][kx-px].
//
// R4: WEIGHT-STATIONARY WAVE LAYOUT. lane = (cg, oc): oc = lane&15, cg = lane>>4.
// Each lane holds ITS oc's 24 {old,new} weight pairs in 48 VGPRs (loaded once) ->
// zero weight traffic in the loop, every FMA is VGPR*VGPR (v_pk_fma-able).
// x loads are 16-way lane-duplicated (coalescer broadcasts; HBM unchanged).
// Row streaming with packed {old,new} pending pooled rows; 2-deep ping-pong
// prefetch (two explicit buffer sets, no runtime indexing -> no scratch).

#define IC 3
#define OCH 16
#define HH 512
#define WW 512
#define WP 255      // pooled cols
#define L 15        // pooled rows per strip (255 = 17*15)
#define STRIPS 17
#define CB 16       // pooled cols per block (4 waves x 4 cg)
#define NCB 16      // col-blocks (16*16=256 >= 255, last lane-group masked)

typedef float v2f __attribute__((ext_vector_type(2)));
typedef float v4f __attribute__((ext_vector_type(4)));

__device__ __forceinline__ float fast_sigmoid(float v) {
    float e = __expf(-v);                    // v_exp_f32
    return __builtin_amdgcn_rcpf(1.0f + e);  // v_rcp_f32
}

// ws layout: per oc, 64 floats (256B stride):
//   [48] = pair p = (kyp*3+ic)*4+kx, kyp in {0,1}:
//     ws[oc*64 + 2p]   = w_eff[kyp+2][ic][kx]  ("old" pending row -> acc.x)
//     ws[oc*64 + 2p+1] = w_eff[kyp  ][ic][kx]  ("new" pending row -> acc.y)
//   ws[oc*64 + 48] = bias[oc]
__global__ void build_weff(const float* __restrict__ w,
                           const float* __restrict__ bias,
                           float* __restrict__ ws)
{
    const int i = threadIdx.x;
    for (int idx = i; idx < OCH * 48; idx += 256) {
        const int oc = idx / 48;
        const int r  = idx - oc * 48;
        const int tp = r >> 1;            // (kyp*3+ic)*4+kx
        const int which = r & 1;          // 0: old (ky=kyp+2), 1: new (ky=kyp)
        const int kx = tp & 3;
        const int t2 = tp >> 2;
        const int kyp = t2 / 3;
        const int ic  = t2 - kyp * 3;
        const int ky = which ? kyp : (kyp + 2);
        float s = 0.f;
#pragma unroll
        for (int py = 0; py < 2; ++py) {
            int rr = ky - py;
            if (rr < 0 || rr > 2) continue;
#pragma unroll
            for (int px = 0; px < 2; ++px) {
                int cc = kx - px;
                if (cc < 0 || cc > 2) continue;
                s += w[((oc * IC + ic) * 3 + rr) * 3 + cc];
            }
        }
        ws[oc * 64 + r] = 0.25f * s;
    }
    if (i < OCH) ws[i * 64 + 48] = bias[i];
}

// pair P lives in w4[P>>1]: even P -> .xy, odd P -> .zw
#define WPAIR(P) (((P) & 1) ? (v2f){w4[(P) >> 1].z, w4[(P) >> 1].w} \
                            : (v2f){w4[(P) >> 1].x, w4[(P) >> 1].y})

// One input row: 12 taps (3 ic x 4 kx), each one packed FMA into {old,new}.
// Split across acc0/acc1 to halve the dependency chain.
#define TAPS(buf, kyp)                                                   \
    {                                                                    \
        _Pragma("unroll")                                                \
        for (int ic_ = 0; ic_ < IC; ++ic_) {                             \
            _Pragma("unroll")                                            \
            for (int kx_ = 0; kx_ < 4; ++kx_) {                          \
                const float xv_ = (kx_ < 2) ? buf[ic_][0][kx_]           \
                                            : buf[ic_][1][kx_ - 2];      \
                const v2f wp_ = WPAIR(((kyp) * 3 + ic_) * 4 + kx_);      \
                if (((ic_ * 4 + kx_) & 1) == 0) acc0 += wp_ * xv_;       \
                else                            acc1 += wp_ * xv_;       \
            }                                                            \
        }                                                                \
    }

// Load one even/odd row pair into a buffer set (6 x dwordx2 per row).
#define PREFETCH(ebuf, obuf, offe, offo)                                 \
    {                                                                    \
        _Pragma("unroll")                                                \
        for (int ic_ = 0; ic_ < IC; ++ic_) {                             \
            const float* p_ = xr + (size_t)ic_ * (HH * WW);              \
            ebuf[ic_][0] = *(const v2f*)(p_ + (offe));                   \
            ebuf[ic_][1] = *(const v2f*)(p_ + (offe) + 2);               \
            obuf[ic_][0] = *(const v2f*)(p_ + (offo));                   \
            obuf[ic_][1] = *(const v2f*)(p_ + (offo) + 2);               \
        }                                                                \
    }

#define ROTATE { acc0.x = acc0.y; acc0.y = bv;  acc1.x = acc1.y; acc1.y = 0.f; }

__global__ __launch_bounds__(256, 4)
void conv_pool_sig_sum(const float* __restrict__ x,
                       const float* __restrict__ ws,
                       float* __restrict__ out)
{
    const int tid = threadIdx.x;
    const int oc  = tid & 15;                    // lane's output channel
    const int jj  = blockIdx.x * CB + (tid >> 4);// lane's pooled col
    const int j   = (jj < WP) ? jj : (WP - 1);   // clamp (masked later)
    const int b   = blockIdx.y;
    const int r0  = blockIdx.z * L;

    // ---- weight-stationary: this lane's oc column, loaded once ----
    v4f w4[12];
#pragma unroll
    for (int k = 0; k < 12; ++k)
        w4[k] = *(const v4f*)(ws + oc * 64 + 4 * k);
    const float bv = ws[oc * 64 + 48];

    // strip base: input rows 2*r0 .. 2*r0+31, cols 2j..2j+3
    const float* xr = x + (size_t)b * (IC * HH * WW)
                        + (size_t)(2 * r0) * WW + 2 * j;

    v2f eA[IC][2], oA[IC][2], eB[IC][2], oB[IC][2];

#pragma unroll
    for (int ic = 0; ic < IC; ++ic) {
        const float* p = xr + (size_t)ic * (HH * WW);
        eA[ic][0] = *(const v2f*)(p);       eA[ic][1] = *(const v2f*)(p + 2);
        oA[ic][0] = *(const v2f*)(p + WW);  oA[ic][1] = *(const v2f*)(p + WW + 2);
    }

    // acc = {old pending pooled row, new pending pooled row}, split for ILP
    v2f acc0 = {0.f, 0.f}, acc1 = {0.f, 0.f};
    float lsum = 0.f;

    // 16 logical iters u=0..15 (2 per trip). u=0's old slot is garbage
    // (discarded); u=15's new slot is garbage (never read). No edge branches.
#pragma unroll 1
    for (int t = 0; t < L; t += 2) {
        // ---- u = t: compute set A (rows 2u,2u+1), prefetch set B (2u+2,2u+3)
        ROTATE
        PREFETCH(eB, oB, 2 * WW, 3 * WW)   // u<=14 -> rows <=31, never clamps
        TAPS(eA, 0)
        TAPS(oA, 1)
        if (t > 0) lsum += fast_sigmoid(acc0.x + acc1.x);
        xr += 2 * WW;

        // ---- u = t+1: compute set B, prefetch set A (rows 2u+2,2u+3)
        ROTATE
        {
            const int oe = (t < L - 1) ? 2 * WW : WW;  // u==15: clamped dead load
            const int oo = (t < L - 1) ? 3 * WW : WW;
            PREFETCH(eA, oA, oe, oo)
        }
        TAPS(eB, 0)
        TAPS(oB, 1)
        lsum += fast_sigmoid(acc0.x + acc1.x);
        xr += 2 * WW;
    }

    if (jj >= WP) lsum = 0.f;   // drop clamped duplicate lanes (last col-block)

    // wave64 butterfly -> per-block LDS reduce -> ONE atomic per block
#pragma unroll
    for (int off = 32; off > 0; off >>= 1)
        lsum += __shfl_xor(lsum, off, 64);

    __shared__ float red[4];
    if ((tid & 63) == 0) red[tid >> 6] = lsum;
    __syncthreads();
    if (tid == 0)
        atomicAdd(out + b, red[0] + red[1] + red[2] + red[3]);
}

extern "C" void kernel_launch(void* const* d_in, const int* in_sizes, int n_in,
                              void* d_out, int out_size, void* d_ws, size_t ws_size,
                              hipStream_t stream) {
    const float* x = (const float*)d_in[0];
    const float* w = (const float*)d_in[1];
    const float* bias = (const float*)d_in[2];
    float* out = (float*)d_out;
    float* wws = (float*)d_ws;  // 16 * 64 floats = 4 KB

    hipMemsetAsync(out, 0, out_size * sizeof(float), stream);
    build_weff<<<1, 256, 0, stream>>>(w, bias, wws);

    dim3 grid(NCB, 64, STRIPS);  // 16 col-blocks x 64 batches x 17 strips
    conv_pool_sig_sum<<<grid, 256, 0, stream>>>(x, wws, out);
}

// Round 5
// 364.430 us; speedup vs baseline: 1.7113x; 1.7113x over previous
//
#include <hip/hip_runtime.h>

// x: (64,3,512,512) fp32 -> conv3x3 VALID + avgpool2x2 + sigmoid + per-batch sum.
// Fused stride-2 4x4 conv: w_eff[ky][kx] = 0.25*sum_{py,px in {0,1}} w[ky-py][kx-px].
//
// R5: LDS-staged x + WEIGHT-STATIONARY VGPRs.
//  lane = (cg, oc): oc = tid&15 (lane's output channel), cg = tid>>4 (0..15).
//  Each lane: its oc's 24 {old,new} weight pairs in 48 VGPRs, loaded ONCE.
//  Block covers 32 pooled cols (2 per cg lane); x rows staged cooperatively
//  into LDS (coalesced, each byte fetched once per block), consumed via
//  ds_read_b128 with 16-way same-address broadcast (conflict-free).
//  Streaming {old,new} packed accumulators (R4 math, verified); double-buffered
//  row-pair staging: loads issued before compute, ds_write after (T14 overlap).

#define IC 3
#define OCH 16
#define HH 512
#define WW 512
#define WP 255      // pooled cols
#define L 51        // pooled rows per strip (255 = 5*51)
#define STRIPS 5
#define CB 32       // pooled cols per block
#define NCB 8       // 8*32 = 256 >= 255 (last col masked)
#define PADW 68     // staged floats per (ic,row): 2*CB+2 = 66, padded

typedef float v2f __attribute__((ext_vector_type(2)));
typedef float v4f __attribute__((ext_vector_type(4)));

__device__ __forceinline__ float fast_sigmoid(float v) {
    float e = __expf(-v);                    // v_exp_f32
    return __builtin_amdgcn_rcpf(1.0f + e);  // v_rcp_f32
}

// ws layout: per oc, 64 floats (256B stride):
//   pair p = (kyp*3+ic)*4+kx, kyp in {0,1}:
//     ws[oc*64 + 2p]   = w_eff[kyp+2][ic][kx]  ("old" pending row -> acc.x)
//     ws[oc*64 + 2p+1] = w_eff[kyp  ][ic][kx]  ("new" pending row -> acc.y)
//   ws[oc*64 + 48] = bias[oc]            (layout verified correct in R4)
__global__ void build_weff(const float* __restrict__ w,
                           const float* __restrict__ bias,
                           float* __restrict__ ws)
{
    const int i = threadIdx.x;
    for (int idx = i; idx < OCH * 48; idx += 256) {
        const int oc = idx / 48;
        const int r  = idx - oc * 48;
        const int tp = r >> 1;            // (kyp*3+ic)*4+kx
        const int which = r & 1;          // 0: old (ky=kyp+2), 1: new (ky=kyp)
        const int kx = tp & 3;
        const int t2 = tp >> 2;
        const int kyp = t2 / 3;
        const int ic  = t2 - kyp * 3;
        const int ky = which ? kyp : (kyp + 2);
        float s = 0.f;
#pragma unroll
        for (int py = 0; py < 2; ++py) {
            int rr = ky - py;
            if (rr < 0 || rr > 2) continue;
#pragma unroll
            for (int px = 0; px < 2; ++px) {
                int cc = kx - px;
                if (cc < 0 || cc > 2) continue;
                s += w[((oc * IC + ic) * 3 + rr) * 3 + cc];
            }
        }
        ws[oc * 64 + r] = 0.25f * s;
    }
    if (i < OCH) ws[i * 64 + 48] = bias[i];
}

// pair P lives in w4[P>>1]: even P -> .xy, odd P -> .zw
#define WPAIR(P) (((P) & 1) ? (v2f){w4[(P) >> 1].z, w4[(P) >> 1].w} \
                            : (v2f){w4[(P) >> 1].x, w4[(P) >> 1].y})

// One t-step: prefetch-load row-pair TT+1 (regs), rotate, taps on both rows of
// row-pair TT from LDS buf BR, ds_write prefetch to other buf, barrier, emit.
#define BODY(TT, BR, SWW, STG, EMIT)                                      \
  {                                                                       \
    v2f pf;                                                               \
    const bool dost = sact && (STG);                                      \
    if (dost) pf = *(const v2f*)pfp;                                      \
    pfp += 2 * WW;                                                        \
    accA0.x = accA0.y; accA0.y = bv;  accA1.x = accA1.y; accA1.y = 0.f;   \
    accB0.x = accB0.y; accB0.y = bv;  accB1.x = accB1.y; accB1.y = 0.f;   \
    _Pragma("unroll")                                                     \
    for (int par_ = 0; par_ < 2; ++par_) {                                \
      _Pragma("unroll")                                                   \
      for (int ic_ = 0; ic_ < IC; ++ic_) {                                \
        const v4f a_ = *(const v4f*)&sx[BR][ic_][par_][4 * cg];           \
        const v2f t_ = *(const v2f*)&sx[BR][ic_][par_][4 * cg + 4];       \
        const v2f w0_ = WPAIR((par_ * 3 + ic_) * 4 + 0);                  \
        const v2f w1_ = WPAIR((par_ * 3 + ic_) * 4 + 1);                  \
        const v2f w2_ = WPAIR((par_ * 3 + ic_) * 4 + 2);                  \
        const v2f w3_ = WPAIR((par_ * 3 + ic_) * 4 + 3);                  \
        accA0 += w0_ * a_.x;  accA1 += w1_ * a_.y;                        \
        accA0 += w2_ * a_.z;  accA1 += w3_ * a_.w;                        \
        accB0 += w0_ * a_.z;  accB1 += w1_ * a_.w;                        \
        accB0 += w2_ * t_.x;  accB1 += w3_ * t_.y;                        \
      }                                                                   \
    }                                                                     \
    if (dost) *(v2f*)(SWW) = pf;                                          \
    __syncthreads();                                                      \
    if (EMIT) {                                                           \
      lsA += fast_sigmoid(accA0.x + accA1.x);                             \
      lsB += fast_sigmoid(accB0.x + accB1.x);                             \
    }                                                                     \
  }

__global__ __launch_bounds__(256, 4)
void conv_pool_sig_sum(const float* __restrict__ x,
                       const float* __restrict__ ws,
                       float* __restrict__ out)
{
    const int tid = threadIdx.x;
    const int oc  = tid & 15;
    const int cg  = tid >> 4;                 // 0..15: lane's pooled-col pair
    const int b   = blockIdx.y;
    const int j0  = blockIdx.x * CB;
    const int r0  = blockIdx.z * L;

    alignas(16) __shared__ float sx[2][IC][2][PADW];  // [buf][ic][row-par][col]

    // ---- weight-stationary: this lane's oc column, loaded once (48 VGPRs) ----
    v4f w4[12];
#pragma unroll
    for (int k = 0; k < 12; ++k)
        w4[k] = *(const v4f*)(ws + oc * 64 + 4 * k);
    const float bv = ws[oc * 64 + 48];

    // ---- cooperative stage mapping: 2 rows x 3 ic x 66 floats = 198 x 8B ----
    const int ts    = (tid < 198) ? tid : 197;
    const int c     = ts / 33;                // chunk = ic*2 + par
    const int off   = ts - 33 * c;            // 0..32 -> float pair 2off,2off+1
    const int s_ic  = c >> 1;
    const int s_par = c & 1;
    int gc = 2 * j0 + 2 * off;                // global col of this 8B chunk
    if (gc > 510) gc = 510;                   // right-edge clamp (masked lanes only)
    const float* pfp = x + ((size_t)b * IC + s_ic) * (HH * WW)
                         + (size_t)(2 * r0 + s_par) * WW + gc;
    float* const sw0 = &sx[0][s_ic][s_par][2 * off];
    float* const sw1 = &sx[1][s_ic][s_par][2 * off];
    const bool sact = (tid < 198);

    // prologue: stage row-pair 0 into buf0
    if (sact) *(v2f*)sw0 = *(const v2f*)pfp;
    pfp += 2 * WW;
    __syncthreads();

    // packed {old,new} pending pooled rows; even/odd kx split for ILP.
    // colA = j0+2cg (always valid), colB = j0+2cg+1 (masked at 255).
    v2f accA0 = {0.f, 0.f}, accA1 = {0.f, 0.f};
    v2f accB0 = {0.f, 0.f}, accB1 = {0.f, 0.f};
    float lsA = 0.f, lsB = 0.f;

    // t = 0..L (L+1 = 52 steps, hand-unrolled x2 so LDS buffer is static).
    // t=0: old slot garbage (not emitted). t=L: new slot garbage (never read).
#pragma unroll 1
    for (int tt = 0; tt < L + 1; tt += 2) {
        BODY(tt,     0, sw1, true,          tt > 0)
        BODY(tt + 1, 1, sw0, (tt + 1) < L,  true)
    }

    if (j0 + 2 * cg + 1 >= WP) lsB = 0.f;     // drop pooled col 255
    float lsum = lsA + lsB;

    // wave64 butterfly -> per-block LDS reduce -> ONE atomic per block
#pragma unroll
    for (int off2 = 32; off2 > 0; off2 >>= 1)
        lsum += __shfl_xor(lsum, off2, 64);

    __shared__ float red[4];
    if ((tid & 63) == 0) red[tid >> 6] = lsum;
    __syncthreads();
    if (tid == 0)
        atomicAdd(out + b, red[0] + red[1] + red[2] + red[3]);
}

extern "C" void kernel_launch(void* const* d_in, const int* in_sizes, int n_in,
                              void* d_out, int out_size, void* d_ws, size_t ws_size,
                              hipStream_t stream) {
    const float* x = (const float*)d_in[0];
    const float* w = (const float*)d_in[1];
    const float* bias = (const float*)d_in[2];
    float* out = (float*)d_out;
    float* wws = (float*)d_ws;  // 16 * 64 floats = 4 KB

    hipMemsetAsync(out, 0, out_size * sizeof(float), stream);
    build_weff<<<1, 256, 0, stream>>>(w, bias, wws);

    dim3 grid(NCB, 64, STRIPS);  // 8 col-blocks x 64 batches x 5 strips = 2560
    conv_pool_sig_sum<<<grid, 256, 0, stream>>>(x, wws, out);
}